// Round 1
// baseline (606.436 us; speedup 1.0000x reference)
//
#include <hip/hip_runtime.h>
#include <hip/hip_bf16.h>
#include <cstdint>
#include <cstddef>

typedef __attribute__((ext_vector_type(8))) short bf16x8;
typedef __attribute__((ext_vector_type(4))) float f32x4;
typedef unsigned short u16;

__device__ __forceinline__ u16 f2bf(float f) {
    unsigned int u = __float_as_uint(f);
    u += 0x7fffu + ((u >> 16) & 1u);   // RNE
    return (u16)(u >> 16);
}

__device__ __forceinline__ void gload16(const void* g, void* l) {
    __builtin_amdgcn_global_load_lds((const __attribute__((address_space(1))) void*)g,
                                     (__attribute__((address_space(3))) void*)l,
                                     16, 0, 0);
}

// ---------------- f32 -> bf16 convert (vectorized, exact-fit grid) -------------
__global__ void cvt_f32_bf16(const float* __restrict__ in, u16* __restrict__ out, int n4) {
    int i = blockIdx.x * blockDim.x + threadIdx.x;
    if (i < n4) {
        float4 v = ((const float4*)in)[i];
        ushort4 o;
        o.x = f2bf(v.x); o.y = f2bf(v.y); o.z = f2bf(v.z); o.w = f2bf(v.w);
        ((ushort4*)out)[i] = o;
    }
}

// ---------------- fused expert GEMM layer ------------------------------------
// out[b,n] = act( sum_e gate[b,e] * ( sum_k A[b,k]*Bw[e,n,k] + bias[e,n] ) )
// A: [M,K] bf16 row-major. Bw: [NE,N,K] bf16 (output-dim major, contraction minor).
// gate: [M,NE] f32. bias: [NE,N] f32.
// Tile: BM=BN=128, BK=64, 256 threads (4 waves, 2x2), wave computes 64x64.
template<bool ELU_ACT, bool OUT_BF16>
__global__ void moe_layer(const u16* __restrict__ A,
                          const u16* __restrict__ Bw,
                          const float* __restrict__ gate,
                          const float* __restrict__ bias,
                          void* __restrict__ outp,
                          int N, int K) {
    constexpr int BM = 128, BN = 128, BK = 64, NE = 8;
    __shared__ u16 As[BM * BK];      // 16 KB, swizzled rows of 128B
    __shared__ u16 Bs[BN * BK];      // 16 KB
    __shared__ float Ws[BM * NE];    // 4 KB  gates
    __shared__ float BiasS[NE * BN]; // 4 KB

    const int tid  = threadIdx.x;
    const int lane = tid & 63;
    const int wave = tid >> 6;
    const int wr = wave >> 1, wc = wave & 1;
    const int fr = lane & 15;      // A-row / B-col / C-col within 16x16 frag
    const int fg = lane >> 4;      // k-group (input), row-group (C/D)
    const int m0 = blockIdx.y * BM;
    const int n0 = blockIdx.x * BN;

    // stage gates + bias tile (exactly 1024 floats each, 4 per thread)
    {
        const int j = tid * 4;
        *(float4*)&Ws[j]    = *(const float4*)&gate[(size_t)(m0 + (j >> 3)) * NE + (j & 7)];
        *(float4*)&BiasS[j] = *(const float4*)&bias[(size_t)(j >> 7) * N + n0 + (j & 127)];
    }

    f32x4 tot[4][4];
    #pragma unroll
    for (int a = 0; a < 4; ++a)
        #pragma unroll
        for (int b = 0; b < 4; ++b) tot[a][b] = f32x4{0.f, 0.f, 0.f, 0.f};

    const char* Abase = (const char*)(A + (size_t)m0 * K);
    const int swz = (fr & 7) << 4;   // read-side XOR swizzle (row&7 == fr&7 here)
    const int nkt = K / BK;

    for (int e = 0; e < NE; ++e) {
        f32x4 acc[4][4];
        #pragma unroll
        for (int a = 0; a < 4; ++a)
            #pragma unroll
            for (int b = 0; b < 4; ++b) acc[a][b] = f32x4{0.f, 0.f, 0.f, 0.f};

        const char* Bbase = (const char*)(Bw + ((size_t)e * N + n0) * K);

        for (int kt = 0; kt < nkt; ++kt) {
            __syncthreads();   // previous tile's reads done
            const int kB = kt * BK * 2;    // byte offset along K
            #pragma unroll
            for (int it = 0; it < 4; ++it) {
                const int c   = it * 4 + wave;        // chunk 0..15 (1024B each)
                const int L   = c * 1024 + lane * 16; // this lane's linear LDS byte
                const int row = L >> 7;               // 128B per row (BK=64 bf16)
                const int cb  = (L & 127) ^ ((row & 7) << 4); // inverse-swizzled src col
                gload16(Abase + (size_t)row * (K * 2) + kB + cb, (char*)As + c * 1024);
                gload16(Bbase + (size_t)row * (K * 2) + kB + cb, (char*)Bs + c * 1024);
            }
            __syncthreads();   // staged data visible (vmcnt drained by barrier)

            #pragma unroll
            for (int kk = 0; kk < 2; ++kk) {
                const int kb = kk * 64 + fg * 16;     // byte col of this lane's 8 bf16
                bf16x8 af[4], bfr[4];
                #pragma unroll
                for (int mi = 0; mi < 4; ++mi) {
                    const int r  = wr * 64 + mi * 16 + fr;
                    af[mi]  = *(const bf16x8*)((const char*)As + r * 128 + (kb ^ swz));
                    const int cc = wc * 64 + mi * 16 + fr;
                    bfr[mi] = *(const bf16x8*)((const char*)Bs + cc * 128 + (kb ^ swz));
                }
                #pragma unroll
                for (int mi = 0; mi < 4; ++mi)
                    #pragma unroll
                    for (int ni = 0; ni < 4; ++ni)
                        acc[mi][ni] = __builtin_amdgcn_mfma_f32_16x16x32_bf16(
                            af[mi], bfr[ni], acc[mi][ni], 0, 0, 0);
            }
        }

        // fold expert partial into total with per-row gate weight
        #pragma unroll
        for (int mi = 0; mi < 4; ++mi) {
            #pragma unroll
            for (int j = 0; j < 4; ++j) {
                const int r = wr * 64 + mi * 16 + fg * 4 + j;
                const float w = Ws[r * NE + e];
                #pragma unroll
                for (int ni = 0; ni < 4; ++ni) tot[mi][ni][j] += w * acc[mi][ni][j];
            }
        }
    }

    // epilogue: gate-weighted bias, activation, store
    float bias8[4][8];
    #pragma unroll
    for (int ni = 0; ni < 4; ++ni)
        #pragma unroll
        for (int e = 0; e < 8; ++e)
            bias8[ni][e] = BiasS[e * BN + wc * 64 + ni * 16 + fr];

    #pragma unroll
    for (int mi = 0; mi < 4; ++mi) {
        #pragma unroll
        for (int j = 0; j < 4; ++j) {
            const int r = wr * 64 + mi * 16 + fg * 4 + j;
            float g8[8];
            #pragma unroll
            for (int e = 0; e < 8; ++e) g8[e] = Ws[r * NE + e];
            #pragma unroll
            for (int ni = 0; ni < 4; ++ni) {
                float v = tot[mi][ni][j];
                #pragma unroll
                for (int e = 0; e < 8; ++e) v += g8[e] * bias8[ni][e];
                if (ELU_ACT) v = (v > 0.f) ? v : expm1f(v);
                const int cl = wc * 64 + ni * 16 + fr;
                const size_t off = (size_t)(m0 + r) * N + n0 + cl;
                if (OUT_BF16) ((u16*)outp)[off]  = f2bf(v);
                else          ((float*)outp)[off] = v;
            }
        }
    }
}

// ---------------- launcher ----------------------------------------------------
extern "C" void kernel_launch(void* const* d_in, const int* in_sizes, int n_in,
                              void* d_out, int out_size, void* d_ws, size_t ws_size,
                              hipStream_t stream) {
    const float* X  = (const float*)d_in[0];   // [8192,512]
    const float* W  = (const float*)d_in[1];   // [8192,8]
    const float* W1 = (const float*)d_in[2];   // [8,1024,512]
    const float* b1 = (const float*)d_in[3];   // [8,1024]
    const float* W2 = (const float*)d_in[4];   // [8,1024,1024]
    const float* b2 = (const float*)d_in[5];   // [8,1024]
    const float* W3 = (const float*)d_in[6];   // [8,512,1024]
    const float* b3 = (const float*)d_in[7];   // [8,512]
    float* out = (float*)d_out;

    char* ws = (char*)d_ws;
    u16* Xb   = (u16*)ws;  ws += (size_t)8192 * 512 * 2;
    u16* W1b  = (u16*)ws;  ws += (size_t)8 * 1024 * 512 * 2;
    u16* W2b  = (u16*)ws;  ws += (size_t)8 * 1024 * 1024 * 2;
    u16* W3b  = (u16*)ws;  ws += (size_t)8 * 512 * 1024 * 2;
    u16* mid1 = (u16*)ws;  ws += (size_t)8192 * 1024 * 2;
    u16* mid2 = (u16*)ws;  ws += (size_t)8192 * 1024 * 2;

    // converts (all element counts divisible by 1024)
    cvt_f32_bf16<<<4096, 256, 0, stream>>>(X,  Xb,  4194304 / 4);
    cvt_f32_bf16<<<4096, 256, 0, stream>>>(W1, W1b, 4194304 / 4);
    cvt_f32_bf16<<<8192, 256, 0, stream>>>(W2, W2b, 8388608 / 4);
    cvt_f32_bf16<<<4096, 256, 0, stream>>>(W3, W3b, 4194304 / 4);

    dim3 blk(256);
    // L1: A=Xb [8192,512], Bw=W1b [8,1024,512] -> mid1 [8192,1024] (ELU)
    moe_layer<true, true><<<dim3(1024 / 128, 8192 / 128), blk, 0, stream>>>(
        Xb, W1b, W, b1, (void*)mid1, 1024, 512);
    // L2: A=mid1 [8192,1024], Bw=W2b [8,1024,1024] -> mid2 [8192,1024] (ELU)
    moe_layer<true, true><<<dim3(1024 / 128, 8192 / 128), blk, 0, stream>>>(
        mid1, W2b, W, b2, (void*)mid2, 1024, 1024);
    // L3: A=mid2 [8192,1024], Bw=W3b [8,512,1024] -> out [8192,512] (no act, f32)
    moe_layer<false, false><<<dim3(512 / 128, 8192 / 128), blk, 0, stream>>>(
        mid2, W3b, W, b3, (void*)out, 512, 1024);
}